// Round 9
// baseline (1103.770 us; speedup 1.0000x reference)
//
#include <hip/hip_runtime.h>

#define TT 2048
#define SS 128
#define DMAXX 128
#define NBATCH 64

typedef float f2 __attribute__((ext_vector_type(2)));

__device__ __forceinline__ float fexp2(float x){ return __builtin_amdgcn_exp2f(x); }
__device__ __forceinline__ float flog2(float x){ return __builtin_amdgcn_logf(x); }
__device__ __forceinline__ float frcp (float x){ return __builtin_amdgcn_rcpf(x); }
__device__ __forceinline__ f2 pkfma(f2 a, f2 b, f2 c){ return __builtin_elementwise_fma(a, b, c); }

template<int CTRL>
__device__ __forceinline__ float dppf(float x) {
    int i = __float_as_int(x);
    return __int_as_float(__builtin_amdgcn_update_dpp(i, i, CTRL, 0xF, 0xF, false));
}
#define DPP_XOR1   0xB1  // quad_perm(1,0,3,2)
#define DPP_XOR2   0x4E  // quad_perm(2,3,0,1)
#define DPP_SHUP1  0x90  // quad_perm(0,0,1,2)
#define DPP_ROR4   0x124
#define DPP_ROR8   0x128
#define DPP_BC15   0x142
#define DPP_BC31   0x143

constexpr float LOG2E = 1.4426950408889634f;
constexpr float LN2   = 0.6931471805599453f;

// j = tid>>2 (state), q = tid&3 (lag chunk). Ring register-renamed; renorm every
// 8 steps (exact). Trans: lane l reads U float4s #(l&31), #((l+16)&31) (2 LDS
// insts/wave, stride-1 banks); the f2 partial-accumulator rotates around the
// 16-lane row (row_ror:4 ×4 = home) picking up each visited lane's 8 floats
// against eA[i_own][j_visitor]. Quad lanes own disjoint i-quarters (m mod 4),
// so the quad XOR-reduce yields the full Etrans[j].
struct State {
    f2    rp[16];      // ring: at end of step t, slot s holds lag pos (s+t+1)&31
    f2    eAj[4][4];   // phase h, reg c: (eA[i0][j_h], eA[i0+1][j_h])
    float eD[32];      // exp(D[j][32q+k])
    float eD0;         // exp(D[j][0]) — lag-1 weight for the fresh slot
    float pf[4];       // logB prefetch, distance 4
    const float* pfp;  // prefetch pointer, advanced SS/step
    float C2;          // accumulated log2(m)
    float e_pi;
};

struct Ctx {
    const float4* upA0; const float4* upA1;  // float4 #(l&31)
    const float4* upB0; const float4* upB1;  // float4 #((l+16)&31)
    const f2*     wmp;                       // renorm read: (wm[2q], wm[2q+1])
    float* uaw0; float* uaw1;                // U write (q==0 lanes)
    float* wmwp;                             // wave-max write (lane 63)
    bool q0, l63;
};

template<int PHI>
__device__ __forceinline__ void hsmm_step(State& st, const Ctx& c, int tb)
{
    constexpr int  rho   = 31 - PHI;          // slot receiving the fresh (lag-1) datum
    constexpr int  pb    = (PHI + 1) & 1;
    constexpr int  wb    = PHI & 1;
    constexpr bool DO_WM = ((PHI & 7) == 6);
    constexpr bool DO_RN = ((PHI & 7) == 7);
    const int t = tb + PHI;

    // ---- issue the two distributed U reads ----
    float4 vA = *(pb ? c.upA1 : c.upA0);
    float4 vB = *(pb ? c.upB1 : c.upB0);

    // ---- step multiplier g (no LDS on 7/8 steps) ----
    float xB = st.pf[PHI & 3];                 // logB[t]
    if (t + 4 < TT) st.pf[PHI & 3] = st.pfp[0];
    st.pfp += SS;
    float g = fexp2(xB * LOG2E);
    if constexpr (DO_RN) {
        f2 wv = *c.wmp;                        // 2 of 8 wave maxes (written at PHI-1)
        float m = fmaxf(wv.x, wv.y);
        m = fmaxf(m, dppf<DPP_XOR1>(m));
        m = fmaxf(m, dppf<DPP_XOR2>(m));       // max over all 8 waves
        st.C2 += flog2(m);
        g *= frcp(m);
    }

    // ---- ring: carry expiring slot, scale, insert (q0: 0 now, patched later) ----
    float rold;
    if constexpr (rho & 1) rold = st.rp[rho >> 1].y; else rold = st.rp[rho >> 1].x;
    float car  = dppf<DPP_SHUP1>(rold);
    float insg = (c.q0 ? 0.f : car) * g;
    f2 gg = {g, g};
#pragma unroll
    for (int m2 = 0; m2 < 16; ++m2) st.rp[m2] = st.rp[m2] * gg;
    if constexpr (rho & 1) st.rp[rho >> 1].y = insg;
    else                   st.rp[rho >> 1].x = insg;

    // ---- duration sum: scalar FMAs, rotating index (R7-verified) ----
    float d0 = 0.f, d1 = 0.f, d2 = 0.f, d3 = 0.f;
#pragma unroll
    for (int m2 = 0; m2 < 16; m2 += 2) {
        d0 = fmaf(st.rp[m2].x,     st.eD[(2 * m2 + PHI + 1) & 31], d0);
        d1 = fmaf(st.rp[m2].y,     st.eD[(2 * m2 + PHI + 2) & 31], d1);
        d2 = fmaf(st.rp[m2 + 1].x, st.eD[(2 * m2 + PHI + 3) & 31], d2);
        d3 = fmaf(st.rp[m2 + 1].y, st.eD[(2 * m2 + PHI + 4) & 31], d3);
    }
    float ds = (d0 + d1) + (d2 + d3);
    ds += dppf<DPP_XOR1>(ds);
    ds += dppf<DPP_XOR2>(ds);                  // lags 2..128 (quad-uniform)

    // ---- trans: traveling accumulator, 4 phases around the 16-lane row ----
    f2 r01 = {vA.x, vA.y}, r23 = {vA.z, vA.w};
    f2 r45 = {vB.x, vB.y}, r67 = {vB.z, vB.w};
    f2 acc =       r01 * st.eAj[0][0];
    acc = pkfma(r23, st.eAj[0][1], acc);
    acc = pkfma(r45, st.eAj[0][2], acc);
    acc = pkfma(r67, st.eAj[0][3], acc);
#pragma unroll
    for (int h = 1; h < 4; ++h) {
        acc.x = dppf<DPP_ROR4>(acc.x);
        acc.y = dppf<DPP_ROR4>(acc.y);
        acc = pkfma(r01, st.eAj[h][0], acc);
        acc = pkfma(r23, st.eAj[h][1], acc);
        acc = pkfma(r45, st.eAj[h][2], acc);
        acc = pkfma(r67, st.eAj[h][3], acc);
    }
    acc.x = dppf<DPP_ROR4>(acc.x);             // 4th rotation: acc returns home
    acc.y = dppf<DPP_ROR4>(acc.y);
    float tp = acc.x + acc.y;                  // partial over i-quarter (m mod 4)
    tp += dppf<DPP_XOR1>(tp);
    tp += dppf<DPP_XOR2>(tp);                  // full Etrans[j], quad-uniform
    if constexpr (PHI == 0) { if (tb == 0) tp = st.e_pi; }   // t==0: entry = pi

    // ---- join + patch + write ----
    float tpg = tp * g;
    float U = fmaf(tpg, st.eD0, ds);
    if (c.q0) {
        if constexpr (rho & 1) st.rp[rho >> 1].y = tpg;
        else                   st.rp[rho >> 1].x = tpg;
    }
    if (c.q0) *(wb ? c.uaw1 : c.uaw0) = U;

    // ---- wave max only on pre-renorm steps ----
    if constexpr (DO_WM) {
        float wm = U;
        wm = fmaxf(wm, dppf<DPP_ROR4>(wm));
        wm = fmaxf(wm, dppf<DPP_ROR8>(wm));
        wm = fmaxf(wm, dppf<DPP_BC15>(wm));
        wm = fmaxf(wm, dppf<DPP_BC31>(wm));
        if (c.l63) *c.wmwp = wm;
    }

    asm volatile("s_waitcnt lgkmcnt(0)\n\ts_barrier" ::: "memory");
}

__launch_bounds__(512, 2)
__global__ void hsmm_fwd_kernel(const float* __restrict__ logB,
                                const float* __restrict__ pi,
                                const float* __restrict__ A,
                                const float* __restrict__ D,
                                float* __restrict__ out)
{
    const int b   = blockIdx.x;
    const int tid = threadIdx.x;
    const int l   = tid & 63;
    const int w   = tid >> 6;
    const int j   = tid >> 2;
    const int q   = tid & 3;

    __shared__ __align__(16) float ua[2][SS];   // contiguous: float4 #k at [4k]
    __shared__ __align__(16) float wmaxf[8];

    // runtime-resolve row_ror:4 direction (verified probe method)
    int got4 = __builtin_amdgcn_update_dpp(l, l, DPP_ROR4, 0xF, 0xF, false);
    bool dirA = (got4 == ((l & ~15) | ((l + 4) & 15)));

    State st;
    {
        const int m  = l & 15;
        const int KA = l & 31;
        const int KB = (l + 16) & 31;
#pragma unroll
        for (int h = 0; h < 4; ++h) {
            int mv = dirA ? ((m + 4 * h) & 15) : ((m - 4 * h) & 15);
            int u  = (l & ~15) | mv;            // in-wave lane whose acc visits at phase h
            int jv = 16 * w + (u >> 2);         // that lane's state
#pragma unroll
            for (int cc = 0; cc < 4; ++cc) {
                int K  = (cc < 2) ? KA : KB;
                int i0 = 4 * K + 2 * (cc & 1);
                st.eAj[h][cc].x = fexp2(A[(i0)     * SS + jv] * LOG2E);
                st.eAj[h][cc].y = fexp2(A[(i0 + 1) * SS + jv] * LOG2E);
            }
        }
    }
#pragma unroll
    for (int k = 0; k < 32; ++k)
        st.eD[k] = fexp2(D[j * DMAXX + q * 32 + k] * LOG2E);
#pragma unroll
    for (int k = 0; k < 16; ++k) st.rp[k] = (f2){0.f, 0.f};
    st.eD0  = fexp2(D[j * DMAXX] * LOG2E);
    st.C2   = 0.f;
    st.e_pi = fexp2(pi[j] * LOG2E);

    const float* __restrict__ lb = logB + ((size_t)b * TT) * SS + j;
#pragma unroll
    for (int k = 0; k < 4; ++k) st.pf[k] = lb[(size_t)k * SS];
    st.pfp = lb + (size_t)4 * SS;

    Ctx c;
    c.upA0 = (const float4*)&ua[0][4 * (l & 31)];
    c.upA1 = (const float4*)&ua[1][4 * (l & 31)];
    c.upB0 = (const float4*)&ua[0][4 * ((l + 16) & 31)];
    c.upB1 = (const float4*)&ua[1][4 * ((l + 16) & 31)];
    c.wmp  = (const f2*)&wmaxf[2 * q];
    c.q0   = (q == 0);
    c.l63  = (l == 63);
    c.uaw0 = &ua[0][j];
    c.uaw1 = &ua[1][j];
    c.wmwp = &wmaxf[w];

    for (int tb = 0; tb < TT; tb += 32) {
        hsmm_step< 0>(st, c, tb); hsmm_step< 1>(st, c, tb);
        hsmm_step< 2>(st, c, tb); hsmm_step< 3>(st, c, tb);
        hsmm_step< 4>(st, c, tb); hsmm_step< 5>(st, c, tb);
        hsmm_step< 6>(st, c, tb); hsmm_step< 7>(st, c, tb);
        hsmm_step< 8>(st, c, tb); hsmm_step< 9>(st, c, tb);
        hsmm_step<10>(st, c, tb); hsmm_step<11>(st, c, tb);
        hsmm_step<12>(st, c, tb); hsmm_step<13>(st, c, tb);
        hsmm_step<14>(st, c, tb); hsmm_step<15>(st, c, tb);
        hsmm_step<16>(st, c, tb); hsmm_step<17>(st, c, tb);
        hsmm_step<18>(st, c, tb); hsmm_step<19>(st, c, tb);
        hsmm_step<20>(st, c, tb); hsmm_step<21>(st, c, tb);
        hsmm_step<22>(st, c, tb); hsmm_step<23>(st, c, tb);
        hsmm_step<24>(st, c, tb); hsmm_step<25>(st, c, tb);
        hsmm_step<26>(st, c, tb); hsmm_step<27>(st, c, tb);
        hsmm_step<28>(st, c, tb); hsmm_step<29>(st, c, tb);
        hsmm_step<30>(st, c, tb); hsmm_step<31>(st, c, tb);
    }

    // epilogue: out[b] = (C2 + log2(sum_j U_{T-1}[j])) * ln2 ;  (T-1)&1 == 1
    if (tid == 0) {
        float s = 0.f;
        for (int i = 0; i < SS; ++i) s += ua[1][i];
        out[b] = (st.C2 + flog2(s)) * LN2;
    }
}

extern "C" void kernel_launch(void* const* d_in, const int* in_sizes, int n_in,
                              void* d_out, int out_size, void* d_ws, size_t ws_size,
                              hipStream_t stream) {
    const float* logB = (const float*)d_in[0];   // (64, 2048, 128) f32
    const float* pi   = (const float*)d_in[1];   // (128,) f32
    const float* A    = (const float*)d_in[2];   // (128, 128) f32
    const float* D    = (const float*)d_in[3];   // (128, 128) f32
    float* out        = (float*)d_out;           // (64,) f32
    hipLaunchKernelGGL(hsmm_fwd_kernel, dim3(NBATCH), dim3(512), 0, stream,
                       logB, pi, A, D, out);
}